// Round 15
// baseline (254.176 us; speedup 1.0000x reference)
//
#include <hip/hip_runtime.h>
#include <stdint.h>

typedef __bf16 bf16x8 __attribute__((ext_vector_type(8)));
typedef __bf16 bf16x4 __attribute__((ext_vector_type(4)));
typedef float f32x4 __attribute__((ext_vector_type(4)));
typedef float f32x16 __attribute__((ext_vector_type(16)));

#define PSCALE (0.125f / 2048.0f)

// async global->LDS, 16B per lane. LDS dest must be wave-uniform; HW adds lane*16.
#define GLOAD16(src, dst)                                                      \
  __builtin_amdgcn_global_load_lds(                                            \
      (__attribute__((address_space(1))) void*)const_cast<__bf16*>(src),       \
      (__attribute__((address_space(3))) void*)(dst), 16, 0, 0)

// -------- prep: LayerNorm (blocks 0..8191) + w_qkv transpose (8192..8959)
//          + w_out transpose (8960..9215), all fp32 -> bf16 ----------------
__global__ __launch_bounds__(256) void prep(
    const float* __restrict__ x, const float* __restrict__ lw,
    const float* __restrict__ lb, __bf16* __restrict__ xn,
    const float* __restrict__ w_qkv, __bf16* __restrict__ Wt1,
    const float* __restrict__ w_out, __bf16* __restrict__ Wt2) {
  __shared__ __bf16 T[64][72];
  __shared__ float red[8];
  const int b = blockIdx.x;
  const int t = threadIdx.x;
  if (b < 8192) {  // ---- LayerNorm row b ----
    const float4 v = ((const float4*)(x + (size_t)b * 1024))[t];
    float s = v.x + v.y + v.z + v.w;
    float ss = v.x * v.x + v.y * v.y + v.z * v.z + v.w * v.w;
#pragma unroll
    for (int o = 32; o; o >>= 1) {
      s += __shfl_down(s, o);
      ss += __shfl_down(ss, o);
    }
    if ((t & 63) == 0) {
      red[t >> 6] = s;
      red[4 + (t >> 6)] = ss;
    }
    __syncthreads();
    const float tot = red[0] + red[1] + red[2] + red[3];
    const float tot2 = red[4] + red[5] + red[6] + red[7];
    const float mu = tot * (1.0f / 1024.0f);
    const float var = tot2 * (1.0f / 1024.0f) - mu * mu;
    const float rs = rsqrtf(var + 1e-5f);
    const float4 wv = ((const float4*)lw)[t];
    const float4 bv = ((const float4*)lb)[t];
    bf16x4 o;
    o[0] = (__bf16)((v.x - mu) * rs * wv.x + bv.x);
    o[1] = (__bf16)((v.y - mu) * rs * wv.y + bv.y);
    o[2] = (__bf16)((v.z - mu) * rs * wv.z + bv.z);
    o[3] = (__bf16)((v.w - mu) * rs * wv.w + bv.w);
    ((bf16x4*)xn)[(size_t)b * 256 + t] = o;
    return;
  }
  // ---- transpose+cvt 64x64 tile: A[R][C] -> At[C][R] ----
  const float* A;
  __bf16* At;
  int R, C, bx, by;
  if (b < 8960) {
    const int ti = b - 8192;           // 768 tiles: 48 x 16
    A = w_qkv; At = Wt1; R = 1024; C = 3072;
    bx = ti % 48; by = ti / 48;
  } else {
    const int ti = b - 8960;           // 256 tiles: 16 x 16
    A = w_out; At = Wt2; R = 1024; C = 1024;
    bx = ti % 16; by = ti / 16;
  }
  const int rb = by * 64, cb = bx * 64;
  const int r = t >> 2, cg = t & 3;
#pragma unroll
  for (int k = 0; k < 4; ++k) {
    const float4 v =
        *(const float4*)(A + (size_t)(rb + r) * C + cb + cg * 16 + k * 4);
    T[cg * 16 + k * 4 + 0][r] = (__bf16)v.x;
    T[cg * 16 + k * 4 + 1][r] = (__bf16)v.y;
    T[cg * 16 + k * 4 + 2][r] = (__bf16)v.z;
    T[cg * 16 + k * 4 + 3][r] = (__bf16)v.w;
  }
  __syncthreads();
#pragma unroll
  for (int i = 0; i < 2; ++i) {
    const int j = i * 256 + t;
    const int c = j >> 3, s8 = j & 7;
    const bf16x8 o = *(const bf16x8*)&T[c][s8 * 8];
    *(bf16x8*)(At + (size_t)(cb + c) * R + rb + s8 * 8) = o;
  }
}

// ---------------- NT-GEMM v2: C[M][N] = A[M][K] * B[N][K]^T ----------------
// (structure unchanged) 128x256 tile, BK=64, 512 thr / 8 waves, 3-buffer LDS,
// lead-2 counted vmcnt(6), staging split around ks=0 MFMA, XCD-chunked remap.
// MODE 0: Q written in FRAGMENT layout (group stride 2048 -- R14 bugfix) with
// PSCALE folded.
template <int MODE>
__global__ __launch_bounds__(512) void gemm_nt(
    const __bf16* __restrict__ A, const __bf16* __restrict__ B, int K,
    float* __restrict__ outF, __bf16* __restrict__ Qo, __bf16* __restrict__ Ko,
    __bf16* __restrict__ Vto, const float* __restrict__ bias) {
  __shared__ __bf16 Sm[3 * 24576];  // per buf: A[128][64] @0, B[256][64] @8192
  const int tid = threadIdx.x;
  const int lane = tid & 63, w = tid >> 6;
  const int g = lane >> 4, c15 = lane & 15;
  const int wr = w >> 2, wc = w & 3;  // wave tile: rows wr*64, cols wc*64
  const int linear = blockIdx.y * gridDim.x + blockIdx.x;
  const int per = (gridDim.x * gridDim.y) >> 3;
  const int nl = (linear & 7) * per + (linear >> 3);
  const int rb = (nl / gridDim.x) * 128, cb = (nl % gridDim.x) * 256;

  const __bf16* aSp[2];
  const __bf16* bSp[4];
  int aDo[2], bDo[4];
#pragma unroll
  for (int i = 0; i < 2; ++i) {
    const int j = i * 512 + tid, row = j >> 3, slot = j & 7;
    aSp[i] = A + (size_t)(rb + row) * K + ((slot ^ (row & 7)) << 3);
    aDo[i] = i * 4096 + w * 512;
  }
#pragma unroll
  for (int i = 0; i < 4; ++i) {
    const int j = i * 512 + tid, col = j >> 3, slot = j & 7;
    bSp[i] = B + (size_t)(cb + col) * K + ((slot ^ (col & 7)) << 3);
    bDo[i] = 8192 + i * 4096 + w * 512;
  }

  f32x4 acc[4][4] = {};
  const int nkb = K >> 6;  // 16

#pragma unroll
  for (int t = 0; t < 2; ++t) {
    __bf16* dst = Sm + t * 24576;
#pragma unroll
    for (int i = 0; i < 2; ++i) GLOAD16(aSp[i] + t * 64, dst + aDo[i]);
#pragma unroll
    for (int i = 0; i < 4; ++i) GLOAD16(bSp[i] + t * 64, dst + bDo[i]);
  }

  int cur = 0, stg = 2, koff = 128;
  for (int kb = 0; kb < nkb; ++kb) {
    if (kb == nkb - 1) {
      asm volatile("s_waitcnt vmcnt(0)" ::: "memory");
    } else {
      asm volatile("s_waitcnt vmcnt(6)" ::: "memory");
    }
    __builtin_amdgcn_s_barrier();
    const bool do_stage = (kb < nkb - 2);
    __bf16* sdst = Sm + stg * 24576;
    if (do_stage) {
#pragma unroll
      for (int i = 0; i < 2; ++i) GLOAD16(aSp[i] + koff, sdst + aDo[i]);
    }
    const __bf16* __restrict__ Ac = Sm + cur * 24576;
    const __bf16* __restrict__ Bc = Ac + 8192;
    // ks = 0
    {
      bf16x8 af[4], bfr[4];
      const int kc = g;
#pragma unroll
      for (int rt = 0; rt < 4; ++rt) {
        const int lr = wr * 64 + rt * 16 + c15;
        af[rt] = *(const bf16x8*)(Ac + lr * 64 + ((kc ^ (lr & 7)) << 3));
      }
#pragma unroll
      for (int ct = 0; ct < 4; ++ct) {
        const int lc = wc * 64 + ct * 16 + c15;
        bfr[ct] = *(const bf16x8*)(Bc + lc * 64 + ((kc ^ (lc & 7)) << 3));
      }
      __builtin_amdgcn_s_setprio(1);
#pragma unroll
      for (int rt = 0; rt < 4; ++rt)
#pragma unroll
        for (int ct = 0; ct < 4; ++ct)
          acc[rt][ct] = __builtin_amdgcn_mfma_f32_16x16x32_bf16(
              af[rt], bfr[ct], acc[rt][ct], 0, 0, 0);
      __builtin_amdgcn_s_setprio(0);
    }
    if (do_stage) {
#pragma unroll
      for (int i = 0; i < 4; ++i) GLOAD16(bSp[i] + koff, sdst + bDo[i]);
      koff += 64;
    }
    // ks = 1
    {
      bf16x8 af[4], bfr[4];
      const int kc = 4 + g;
#pragma unroll
      for (int rt = 0; rt < 4; ++rt) {
        const int lr = wr * 64 + rt * 16 + c15;
        af[rt] = *(const bf16x8*)(Ac + lr * 64 + ((kc ^ (lr & 7)) << 3));
      }
#pragma unroll
      for (int ct = 0; ct < 4; ++ct) {
        const int lc = wc * 64 + ct * 16 + c15;
        bfr[ct] = *(const bf16x8*)(Bc + lc * 64 + ((kc ^ (lc & 7)) << 3));
      }
      __builtin_amdgcn_s_setprio(1);
#pragma unroll
      for (int rt = 0; rt < 4; ++rt)
#pragma unroll
        for (int ct = 0; ct < 4; ++ct)
          acc[rt][ct] = __builtin_amdgcn_mfma_f32_16x16x32_bf16(
              af[rt], bfr[ct], acc[rt][ct], 0, 0, 0);
      __builtin_amdgcn_s_setprio(0);
    }
    cur = (cur == 2) ? 0 : cur + 1;
    stg = (stg == 2) ? 0 : stg + 1;
  }
  const int r00 = rb + wr * 64 + g * 4;
  if (MODE == 1) {
#pragma unroll
    for (int ct = 0; ct < 4; ++ct) {
      const int col = cb + wc * 64 + ct * 16 + c15;
      const float bv = bias[col];
#pragma unroll
      for (int rt = 0; rt < 4; ++rt) {
        const int row = r00 + rt * 16;
#pragma unroll
        for (int r = 0; r < 4; ++r)
          outF[(size_t)(row + r) * 1024 + col] = acc[rt][ct][r] + bv;
      }
    }
  } else {
#pragma unroll
    for (int ct = 0; ct < 4; ++ct) {
      const int col = cb + wc * 64 + ct * 16 + c15;  // 0..3071
      const int part = col >> 10, rem = col & 1023;
      const int h = rem >> 6, d = rem & 63;
#pragma unroll
      for (int rt = 0; rt < 4; ++rt) {
        const int row = r00 + rt * 16;  // 0..8191
        const int bi = row >> 11, n = row & 2047;
        const size_t bh = (size_t)bi * 16 + h;
        if (part == 2) {  // V stored transposed: Vt[bh][d][n]
          bf16x4 pv;
#pragma unroll
          for (int r = 0; r < 4; ++r) pv[r] = (__bf16)acc[rt][ct][r];
          *(bf16x4*)(Vto + (bh * 64 + d) * 2048 + n) = pv;
        } else if (part == 0) {
          // Q in FRAGMENT layout (PSCALE folded), GROUP STRIDE 2048:
          // idx = bh*131072 + (n>>5)*2048 + (((d>>4)<<1)|((d>>3)&1))*256
          //       + (n&31)*8 + (d&7)
          const int dw2 = (((d >> 4) << 1) | ((d >> 3) & 1));
#pragma unroll
          for (int r = 0; r < 4; ++r) {
            const int nn = n + r;
            Qo[bh * 131072 + (size_t)(nn >> 5) * 2048 + dw2 * 256 +
               (nn & 31) * 8 + (d & 7)] = (__bf16)(acc[rt][ct][r] * PSCALE);
          }
        } else {  // K: [bh][n][d]
          __bf16* dst = Ko + (bh * 2048 + n) * 64 + d;
#pragma unroll
          for (int r = 0; r < 4; ++r) dst[(size_t)r * 64] = (__bf16)acc[rt][ct][r];
        }
      }
    }
  }
}

// ------------- fused relu-attention: O = relu(Q' K^T) @ V  (Q' pre-scaled) --
// v10b: pair-split keys (R14 bugfix: Q fragment group stride 4096 -> 2048).
// 8 waves x 512 thr (4 waves/SIMD); wave pair p shares q-rows p*64..+63;
// half 0 handles keys 0..63 of each tile (kb32 0,1), half 1 keys 64..127.
// Per wave per kb: 8 K + 8 V LDS reads feed 32 MFMAs (ratio 0.5 vs R12's 1.0)
// -> DS ~3.8k cyc/CU*kb < MFMA 4.1k. Q streamed from global in FRAGMENT
// layout (b128 coalesced, L1/L2-hot). Pair partials reduced through LDS
// (reusing K/V buffers after the last barrier); even waves write O.
__global__ __launch_bounds__(512, 4) void attn_relu(
    const __bf16* __restrict__ Qf, const __bf16* __restrict__ K,
    const __bf16* __restrict__ Vt, __bf16* __restrict__ O) {
  __shared__ __align__(16) float redF[16384];  // 64 KB: K/V dbuf + reduce
  __bf16* Sb = (__bf16*)redF;  // Ks[buf]=Sb+buf*8192; Vs[buf]=Sb+16384+buf*8192
  const int tid = threadIdx.x;
  const int lane = tid & 63, wv = tid >> 6;  // 8 waves
  const int hi = lane >> 5, c31 = lane & 31;
  const int pair = wv >> 1, half = wv & 1;
  const int bh = blockIdx.x, qb = blockIdx.y;
  const __bf16* Kg = K + (size_t)bh * 2048 * 64;
  const __bf16* Vg = Vt + (size_t)bh * 64 * 2048;
  // fragment-layout Q base for this pair's two 32-q groups (stride 2048)
  const __bf16* Q0 = Qf + (size_t)bh * 131072 +
                     (size_t)(qb * 8 + pair * 2) * 2048 + hi * 256 + c31 * 8;
  const __bf16* Q1 = Q0 + 2048;

  // staging sources (identical swizzles to R12; conflict-free verified):
  const __bf16* kp0;
  const __bf16* kp1;
  const __bf16* vp0;
  const __bf16* vp1;
  {
    const int j0 = tid, j1 = 512 + tid;
    const int X0 = j0 >> 3, s0 = j0 & 7;
    const int X1 = j1 >> 3, s1 = j1 & 7;
    const int K0 = (X0 & ~12) | ((X0 & 4) << 1) | ((X0 & 8) >> 1);
    const int K1 = (X1 & ~12) | ((X1 & 4) << 1) | ((X1 & 8) >> 1);
    kp0 = Kg + (size_t)K0 * 64 + ((s0 ^ (X0 & 7) ^ ((X0 >> 3) & 3)) << 3);
    kp1 = Kg + (size_t)K1 * 64 + ((s1 ^ (X1 & 7) ^ ((X1 >> 3) & 3)) << 3);
    const int d0_ = j0 >> 4, t0_ = j0 & 15;
    const int d1_ = j1 >> 4, t1_ = j1 & 15;
    vp0 = Vg + (size_t)d0_ * 2048 + ((t0_ ^ (d0_ & 15) ^ ((d0_ >> 3) & 3)) << 3);
    vp1 = Vg + (size_t)d1_ * 2048 + ((t1_ ^ (d1_ & 15) ^ ((d1_ >> 3) & 3)) << 3);
  }
  const int dstoff = wv * 512;  // wave-uniform LDS chunk base (elements)

  f32x16 oacc[2][2] = {};  // [qg][dc], partial over this wave's key half

  // prologue: stage tile 0 into buffer 0
  GLOAD16(kp0, Sb + dstoff);
  GLOAD16(kp1, Sb + 4096 + dstoff);
  GLOAD16(vp0, Sb + 16384 + dstoff);
  GLOAD16(vp1, Sb + 16384 + 4096 + dstoff);
  kp0 += 128 * 64; kp1 += 128 * 64; vp0 += 128; vp1 += 128;

  for (int kb = 0; kb < 16; ++kb) {
    const int cur = kb & 1;
    asm volatile("s_waitcnt vmcnt(0)" ::: "memory");
    __builtin_amdgcn_s_barrier();  // cur tile staged for all waves
    const __bf16* __restrict__ Kc = Sb + cur * 8192;
    const __bf16* __restrict__ Vc = Sb + 16384 + cur * 8192;
#pragma unroll
    for (int sub = 0; sub < 2; ++sub) {
      const int kb32 = 2 * half + sub;
      const int R = kb32 * 32 + c31;
      bf16x8 kf[4];
#pragma unroll
      for (int dw = 0; dw < 4; ++dw)
        kf[dw] = *(const bf16x8*)(
            Kc + R * 64 + (((2 * dw + hi) ^ (R & 7) ^ ((R >> 3) & 3)) << 3));
      // QK for qg0 (Q streamed from global, b128 coalesced)
      f32x16 s = {};
      __builtin_amdgcn_s_setprio(1);
#pragma unroll
      for (int dw = 0; dw < 4; ++dw) {
        const bf16x8 q = *(const bf16x8*)(Q0 + dw * 512);
        s = __builtin_amdgcn_mfma_f32_32x32x16_bf16(kf[dw], q, s, 0, 0, 0);
      }
      __builtin_amdgcn_s_setprio(0);
      bf16x8 p0[2];
#pragma unroll
      for (int wl = 0; wl < 2; ++wl)
#pragma unroll
        for (int e = 0; e < 8; ++e)
          p0[wl][e] = (__bf16)fmaxf(s[8 * wl + e], 0.0f);
      // QK for qg1
      f32x16 s2 = {};
      __builtin_amdgcn_s_setprio(1);
#pragma unroll
      for (int dw = 0; dw < 4; ++dw) {
        const bf16x8 q = *(const bf16x8*)(Q1 + dw * 512);
        s2 = __builtin_amdgcn_mfma_f32_32x32x16_bf16(kf[dw], q, s2, 0, 0, 0);
      }
      __builtin_amdgcn_s_setprio(0);
      bf16x8 p1[2];
#pragma unroll
      for (int wl = 0; wl < 2; ++wl)
#pragma unroll
        for (int e = 0; e < 8; ++e)
          p1[wl][e] = (__bf16)fmaxf(s2[8 * wl + e], 0.0f);
      // PV: shared V fragments
      __builtin_amdgcn_s_setprio(1);
#pragma unroll
      for (int wl = 0; wl < 2; ++wl) {
        const int win = 2 * kb32 + wl;
#pragma unroll
        for (int dc = 0; dc < 2; ++dc) {
          const int d = dc * 32 + c31;
          const bf16x8 vb = *(const bf16x8*)(
              Vc + d * 128 +
              (((2 * win + hi) ^ (d & 15) ^ ((d >> 3) & 3)) << 3));
          oacc[0][dc] = __builtin_amdgcn_mfma_f32_32x32x16_bf16(
              p0[wl], vb, oacc[0][dc], 0, 0, 0);
          oacc[1][dc] = __builtin_amdgcn_mfma_f32_32x32x16_bf16(
              p1[wl], vb, oacc[1][dc], 0, 0, 0);
        }
      }
      __builtin_amdgcn_s_setprio(0);
      // stage next tile between the two sub-blocks (lead ~1 tile)
      if (sub == 0 && kb < 15) {
        const int nxt = cur ^ 1;
        GLOAD16(kp0, Sb + nxt * 8192 + dstoff);
        GLOAD16(kp1, Sb + nxt * 8192 + 4096 + dstoff);
        GLOAD16(vp0, Sb + 16384 + nxt * 8192 + dstoff);
        GLOAD16(vp1, Sb + 16384 + nxt * 8192 + 4096 + dstoff);
        kp0 += 128 * 64; kp1 += 128 * 64; vp0 += 128; vp1 += 128;
      }
    }
    __builtin_amdgcn_s_barrier();  // all waves done reading cur before restage
  }
  // ---- pair reduction through LDS (K/V buffers are dead now) ----
  if (half) {
#pragma unroll
    for (int qg = 0; qg < 2; ++qg)
#pragma unroll
      for (int dc = 0; dc < 2; ++dc)
#pragma unroll
        for (int r4 = 0; r4 < 4; ++r4) {
          f32x4 t;
#pragma unroll
          for (int j = 0; j < 4; ++j) t[j] = oacc[qg][dc][r4 * 4 + j];
          *(f32x4*)(redF + pair * 4096 + (qg * 2 + dc) * 1024 + r4 * 256 +
                    lane * 4) = t;
        }
  }
  __builtin_amdgcn_s_barrier();
  if (!half) {
#pragma unroll
    for (int qg = 0; qg < 2; ++qg)
#pragma unroll
      for (int dc = 0; dc < 2; ++dc)
#pragma unroll
        for (int r4 = 0; r4 < 4; ++r4) {
          const f32x4 t = *(const f32x4*)(redF + pair * 4096 +
                                          (qg * 2 + dc) * 1024 + r4 * 256 +
                                          lane * 4);
#pragma unroll
          for (int j = 0; j < 4; ++j) oacc[qg][dc][r4 * 4 + j] += t[j];
        }
    // write O merged-head: [b][n][h*64+d]; q = pair*64+qg*32+(r&3)+8(r>>2)+4hi
    const int bi = bh >> 4, h = bh & 15;
#pragma unroll
    for (int qg = 0; qg < 2; ++qg)
#pragma unroll
      for (int dc = 0; dc < 2; ++dc) {
        const int col = h * 64 + dc * 32 + c31;
#pragma unroll
        for (int r = 0; r < 16; ++r) {
          const int q = pair * 64 + qg * 32 + (r & 3) + 8 * (r >> 2) + 4 * hi;
          const int n0 = qb * 256 + q;
          O[((size_t)bi * 2048 + n0) * 1024 + col] = (__bf16)oacc[qg][dc][r];
        }
      }
  }
}

extern "C" void kernel_launch(void* const* d_in, const int* in_sizes, int n_in,
                              void* d_out, int out_size, void* d_ws,
                              size_t ws_size, hipStream_t stream) {
  (void)in_sizes; (void)n_in; (void)out_size; (void)ws_size;
  const float* x = (const float*)d_in[0];
  const float* ln_w = (const float*)d_in[1];
  const float* ln_b = (const float*)d_in[2];
  const float* w_qkv = (const float*)d_in[3];
  const float* w_out = (const float*)d_in[4];
  const float* b_out = (const float*)d_in[5];
  // d_in[6] = layer_index == 2 (< DEPTH/2) -> relu branch only.
  char* ws = (char*)d_ws;
  __bf16* xn = (__bf16*)(ws);                           // 16 MB
  __bf16* Wt1 = (__bf16*)(ws + (size_t)(16u << 20));    // 6 MB  [3072][1024]
  __bf16* Wt2 = (__bf16*)(ws + (size_t)(22u << 20));    // 2 MB  [1024][1024]
  __bf16* Qb = (__bf16*)(ws + (size_t)(24u << 20));     // 16 MB fragment layout
  __bf16* Kb = (__bf16*)(ws + (size_t)(40u << 20));     // 16 MB [64][2048][64]
  __bf16* Vtb = (__bf16*)(ws + (size_t)(56u << 20));    // 16 MB [64][64][2048]
  __bf16* Ob = (__bf16*)(ws + (size_t)(72u << 20));     // 16 MB [8192][1024]
  float* out = (float*)d_out;

  prep<<<9216, 256, 0, stream>>>(x, ln_w, ln_b, xn, w_qkv, Wt1, w_out, Wt2);
  gemm_nt<0><<<dim3(12, 64), 512, 0, stream>>>(xn, Wt1, 1024, nullptr, Qb, Kb,
                                               Vtb, nullptr);
  attn_relu<<<dim3(64, 8), 512, 0, stream>>>(Qb, Kb, Vtb, Ob);
  gemm_nt<1><<<dim3(4, 64), 512, 0, stream>>>(Ob, Wt2, 1024, out, nullptr,
                                              nullptr, nullptr, b_out);
}

// Round 16
// 182.344 us; speedup vs baseline: 1.3939x; 1.3939x over previous
//
#include <hip/hip_runtime.h>
#include <stdint.h>

typedef __bf16 bf16x8 __attribute__((ext_vector_type(8)));
typedef __bf16 bf16x4 __attribute__((ext_vector_type(4)));
typedef float f32x4 __attribute__((ext_vector_type(4)));
typedef float f32x16 __attribute__((ext_vector_type(16)));

#define PSCALE (0.125f / 2048.0f)

// async global->LDS, 16B per lane. LDS dest must be wave-uniform; HW adds lane*16.
#define GLOAD16(src, dst)                                                      \
  __builtin_amdgcn_global_load_lds(                                            \
      (__attribute__((address_space(1))) void*)const_cast<__bf16*>(src),       \
      (__attribute__((address_space(3))) void*)(dst), 16, 0, 0)

// -------- prep: LayerNorm (blocks 0..8191) + w_qkv transpose (8192..8959)
//          + w_out transpose (8960..9215), all fp32 -> bf16 ----------------
__global__ __launch_bounds__(256) void prep(
    const float* __restrict__ x, const float* __restrict__ lw,
    const float* __restrict__ lb, __bf16* __restrict__ xn,
    const float* __restrict__ w_qkv, __bf16* __restrict__ Wt1,
    const float* __restrict__ w_out, __bf16* __restrict__ Wt2) {
  __shared__ __bf16 T[64][72];
  __shared__ float red[8];
  const int b = blockIdx.x;
  const int t = threadIdx.x;
  if (b < 8192) {  // ---- LayerNorm row b ----
    const float4 v = ((const float4*)(x + (size_t)b * 1024))[t];
    float s = v.x + v.y + v.z + v.w;
    float ss = v.x * v.x + v.y * v.y + v.z * v.z + v.w * v.w;
#pragma unroll
    for (int o = 32; o; o >>= 1) {
      s += __shfl_down(s, o);
      ss += __shfl_down(ss, o);
    }
    if ((t & 63) == 0) {
      red[t >> 6] = s;
      red[4 + (t >> 6)] = ss;
    }
    __syncthreads();
    const float tot = red[0] + red[1] + red[2] + red[3];
    const float tot2 = red[4] + red[5] + red[6] + red[7];
    const float mu = tot * (1.0f / 1024.0f);
    const float var = tot2 * (1.0f / 1024.0f) - mu * mu;
    const float rs = rsqrtf(var + 1e-5f);
    const float4 wv = ((const float4*)lw)[t];
    const float4 bv = ((const float4*)lb)[t];
    bf16x4 o;
    o[0] = (__bf16)((v.x - mu) * rs * wv.x + bv.x);
    o[1] = (__bf16)((v.y - mu) * rs * wv.y + bv.y);
    o[2] = (__bf16)((v.z - mu) * rs * wv.z + bv.z);
    o[3] = (__bf16)((v.w - mu) * rs * wv.w + bv.w);
    ((bf16x4*)xn)[(size_t)b * 256 + t] = o;
    return;
  }
  // ---- transpose+cvt 64x64 tile: A[R][C] -> At[C][R] ----
  const float* A;
  __bf16* At;
  int R, C, bx, by;
  if (b < 8960) {
    const int ti = b - 8192;           // 768 tiles: 48 x 16
    A = w_qkv; At = Wt1; R = 1024; C = 3072;
    bx = ti % 48; by = ti / 48;
  } else {
    const int ti = b - 8960;           // 256 tiles: 16 x 16
    A = w_out; At = Wt2; R = 1024; C = 1024;
    bx = ti % 16; by = ti / 16;
  }
  const int rb = by * 64, cb = bx * 64;
  const int r = t >> 2, cg = t & 3;
#pragma unroll
  for (int k = 0; k < 4; ++k) {
    const float4 v =
        *(const float4*)(A + (size_t)(rb + r) * C + cb + cg * 16 + k * 4);
    T[cg * 16 + k * 4 + 0][r] = (__bf16)v.x;
    T[cg * 16 + k * 4 + 1][r] = (__bf16)v.y;
    T[cg * 16 + k * 4 + 2][r] = (__bf16)v.z;
    T[cg * 16 + k * 4 + 3][r] = (__bf16)v.w;
  }
  __syncthreads();
#pragma unroll
  for (int i = 0; i < 2; ++i) {
    const int j = i * 256 + t;
    const int c = j >> 3, s8 = j & 7;
    const bf16x8 o = *(const bf16x8*)&T[c][s8 * 8];
    *(bf16x8*)(At + (size_t)(cb + c) * R + rb + s8 * 8) = o;
  }
}

// ---------------- NT-GEMM v2: C[M][N] = A[M][K] * B[N][K]^T ----------------
// (unchanged) 128x256 tile, BK=64, 512 thr / 8 waves, 3-buffer LDS,
// lead-2 counted vmcnt(6), staging split around ks=0 MFMA, XCD-chunked remap.
// MODE 0: Q epilogue back to standard [bh][n][d] layout with PSCALE folded.
template <int MODE>
__global__ __launch_bounds__(512) void gemm_nt(
    const __bf16* __restrict__ A, const __bf16* __restrict__ B, int K,
    float* __restrict__ outF, __bf16* __restrict__ Qo, __bf16* __restrict__ Ko,
    __bf16* __restrict__ Vto, const float* __restrict__ bias) {
  __shared__ __bf16 Sm[3 * 24576];  // per buf: A[128][64] @0, B[256][64] @8192
  const int tid = threadIdx.x;
  const int lane = tid & 63, w = tid >> 6;
  const int g = lane >> 4, c15 = lane & 15;
  const int wr = w >> 2, wc = w & 3;  // wave tile: rows wr*64, cols wc*64
  const int linear = blockIdx.y * gridDim.x + blockIdx.x;
  const int per = (gridDim.x * gridDim.y) >> 3;
  const int nl = (linear & 7) * per + (linear >> 3);
  const int rb = (nl / gridDim.x) * 128, cb = (nl % gridDim.x) * 256;

  const __bf16* aSp[2];
  const __bf16* bSp[4];
  int aDo[2], bDo[4];
#pragma unroll
  for (int i = 0; i < 2; ++i) {
    const int j = i * 512 + tid, row = j >> 3, slot = j & 7;
    aSp[i] = A + (size_t)(rb + row) * K + ((slot ^ (row & 7)) << 3);
    aDo[i] = i * 4096 + w * 512;
  }
#pragma unroll
  for (int i = 0; i < 4; ++i) {
    const int j = i * 512 + tid, col = j >> 3, slot = j & 7;
    bSp[i] = B + (size_t)(cb + col) * K + ((slot ^ (col & 7)) << 3);
    bDo[i] = 8192 + i * 4096 + w * 512;
  }

  f32x4 acc[4][4] = {};
  const int nkb = K >> 6;  // 16

#pragma unroll
  for (int t = 0; t < 2; ++t) {
    __bf16* dst = Sm + t * 24576;
#pragma unroll
    for (int i = 0; i < 2; ++i) GLOAD16(aSp[i] + t * 64, dst + aDo[i]);
#pragma unroll
    for (int i = 0; i < 4; ++i) GLOAD16(bSp[i] + t * 64, dst + bDo[i]);
  }

  int cur = 0, stg = 2, koff = 128;
  for (int kb = 0; kb < nkb; ++kb) {
    if (kb == nkb - 1) {
      asm volatile("s_waitcnt vmcnt(0)" ::: "memory");
    } else {
      asm volatile("s_waitcnt vmcnt(6)" ::: "memory");
    }
    __builtin_amdgcn_s_barrier();
    const bool do_stage = (kb < nkb - 2);
    __bf16* sdst = Sm + stg * 24576;
    if (do_stage) {
#pragma unroll
      for (int i = 0; i < 2; ++i) GLOAD16(aSp[i] + koff, sdst + aDo[i]);
    }
    const __bf16* __restrict__ Ac = Sm + cur * 24576;
    const __bf16* __restrict__ Bc = Ac + 8192;
    // ks = 0
    {
      bf16x8 af[4], bfr[4];
      const int kc = g;
#pragma unroll
      for (int rt = 0; rt < 4; ++rt) {
        const int lr = wr * 64 + rt * 16 + c15;
        af[rt] = *(const bf16x8*)(Ac + lr * 64 + ((kc ^ (lr & 7)) << 3));
      }
#pragma unroll
      for (int ct = 0; ct < 4; ++ct) {
        const int lc = wc * 64 + ct * 16 + c15;
        bfr[ct] = *(const bf16x8*)(Bc + lc * 64 + ((kc ^ (lc & 7)) << 3));
      }
      __builtin_amdgcn_s_setprio(1);
#pragma unroll
      for (int rt = 0; rt < 4; ++rt)
#pragma unroll
        for (int ct = 0; ct < 4; ++ct)
          acc[rt][ct] = __builtin_amdgcn_mfma_f32_16x16x32_bf16(
              af[rt], bfr[ct], acc[rt][ct], 0, 0, 0);
      __builtin_amdgcn_s_setprio(0);
    }
    if (do_stage) {
#pragma unroll
      for (int i = 0; i < 4; ++i) GLOAD16(bSp[i] + koff, sdst + bDo[i]);
      koff += 64;
    }
    // ks = 1
    {
      bf16x8 af[4], bfr[4];
      const int kc = 4 + g;
#pragma unroll
      for (int rt = 0; rt < 4; ++rt) {
        const int lr = wr * 64 + rt * 16 + c15;
        af[rt] = *(const bf16x8*)(Ac + lr * 64 + ((kc ^ (lr & 7)) << 3));
      }
#pragma unroll
      for (int ct = 0; ct < 4; ++ct) {
        const int lc = wc * 64 + ct * 16 + c15;
        bfr[ct] = *(const bf16x8*)(Bc + lc * 64 + ((kc ^ (lc & 7)) << 3));
      }
      __builtin_amdgcn_s_setprio(1);
#pragma unroll
      for (int rt = 0; rt < 4; ++rt)
#pragma unroll
        for (int ct = 0; ct < 4; ++ct)
          acc[rt][ct] = __builtin_amdgcn_mfma_f32_16x16x32_bf16(
              af[rt], bfr[ct], acc[rt][ct], 0, 0, 0);
      __builtin_amdgcn_s_setprio(0);
    }
    cur = (cur == 2) ? 0 : cur + 1;
    stg = (stg == 2) ? 0 : stg + 1;
  }
  const int r00 = rb + wr * 64 + g * 4;
  if (MODE == 1) {
#pragma unroll
    for (int ct = 0; ct < 4; ++ct) {
      const int col = cb + wc * 64 + ct * 16 + c15;
      const float bv = bias[col];
#pragma unroll
      for (int rt = 0; rt < 4; ++rt) {
        const int row = r00 + rt * 16;
#pragma unroll
        for (int r = 0; r < 4; ++r)
          outF[(size_t)(row + r) * 1024 + col] = acc[rt][ct][r] + bv;
      }
    }
  } else {
#pragma unroll
    for (int ct = 0; ct < 4; ++ct) {
      const int col = cb + wc * 64 + ct * 16 + c15;  // 0..3071
      const int part = col >> 10, rem = col & 1023;
      const int h = rem >> 6, d = rem & 63;
#pragma unroll
      for (int rt = 0; rt < 4; ++rt) {
        const int row = r00 + rt * 16;  // 0..8191
        const int bi = row >> 11, n = row & 2047;
        const size_t bh = (size_t)bi * 16 + h;
        if (part == 2) {  // V stored transposed: Vt[bh][d][n]
          bf16x4 pv;
#pragma unroll
          for (int r = 0; r < 4; ++r) pv[r] = (__bf16)acc[rt][ct][r];
          *(bf16x4*)(Vto + (bh * 64 + d) * 2048 + n) = pv;
        } else if (part == 0) {  // Q: [bh][n][d], pre-scaled by PSCALE
          __bf16* dst = Qo + (bh * 2048 + n) * 64 + d;
#pragma unroll
          for (int r = 0; r < 4; ++r)
            dst[(size_t)r * 64] = (__bf16)(acc[rt][ct][r] * PSCALE);
        } else {  // K: [bh][n][d]
          __bf16* dst = Ko + (bh * 2048 + n) * 64 + d;
#pragma unroll
          for (int r = 0; r < 4; ++r) dst[(size_t)r * 64] = (__bf16)acc[rt][ct][r];
        }
      }
    }
  }
}

// ------------- fused relu-attention: O = relu(Q' K^T) @ V  (Q' pre-scaled) --
// v11: pair-split keys with Q IN REGISTERS (R15 post-mortem: Q-streaming
// blew per-XCD L2 -> 250MB HBM). 256 thr / 4 waves = 2 pairs x 64 q; half 0
// of each pair takes keys 0..63 (kb32 0,1), half 1 keys 64..127 (kb32 2,3).
// Per wave/kb: 16 LDS reads feed 32 MFMAs (ratio 0.5). Single-buffered K/V
// LDS (32 KB) -> 3 blocks/CU = 12 waves = 3 waves/SIMD (floor(512/VGPR)
// model; target VGPR <= 168); cross-block de-phasing hides the single-buffer
// staging stall (m114). Pair partials reduced via the dead K/V LDS at the
// end; even waves write O. Grid (x=bh, y=qb): XCD=bh%8 -> K+V/XCD = 4MB = L2.
__global__ __launch_bounds__(256) void attn_relu(
    const __bf16* __restrict__ Q, const __bf16* __restrict__ K,
    const __bf16* __restrict__ Vt, __bf16* __restrict__ O) {
  __shared__ __align__(16) float redF[8192];  // 32 KB: K/V buffer + reduce
  __bf16* Sb = (__bf16*)redF;                 // K @0 (8192 el), V @8192
  const int tid = threadIdx.x;
  const int lane = tid & 63, wv = tid >> 6;   // 4 waves
  const int hi = lane >> 5, c31 = lane & 31;
  const int pair = wv >> 1, half = wv & 1;
  const int bh = blockIdx.x, qb = blockIdx.y;  // 16 qb x 128 q
  const __bf16* Qg = Q + ((size_t)bh * 2048 + qb * 128 + pair * 64) * 64;
  const __bf16* Kg = K + (size_t)bh * 2048 * 64;
  const __bf16* Vg = Vt + (size_t)bh * 64 * 2048;

  // staging sources: 2048 16B chunks/tile (K 0..1023, V 1024..2047),
  // 8 per thread. Same conflict-free swizzles as R12 (verified):
  // K: LDS row X holds key kappa(X) (bits 2<->3); slot s = src d-chunk
  //    s ^ (X&7) ^ ((X>>3)&3).  V: row d, slot s = src key-chunk
  //    s ^ (d&15) ^ ((d>>3)&3).
  const __bf16* kp[4];
  const __bf16* vp[4];
#pragma unroll
  for (int i = 0; i < 4; ++i) {
    const int j = i * 256 + tid;
    const int X = j >> 3, s = j & 7;
    const int KX = (X & ~12) | ((X & 4) << 1) | ((X & 8) >> 1);
    kp[i] = Kg + (size_t)KX * 64 + ((s ^ (X & 7) ^ ((X >> 3) & 3)) << 3);
    const int d = j >> 4, sl = j & 15;
    vp[i] = Vg + (size_t)d * 2048 + ((sl ^ (d & 15) ^ ((d >> 3) & 3)) << 3);
  }
  const int dstoff = wv * 512;  // wave-uniform LDS base within 256-chunk group

  // Q held in registers for the whole kernel: q = pair*64 + qg*32 + c31
  bf16x8 qf[2][4];
#pragma unroll
  for (int qg = 0; qg < 2; ++qg)
#pragma unroll
    for (int dw = 0; dw < 4; ++dw)
      qf[qg][dw] =
          *(const bf16x8*)(Qg + (qg * 32 + c31) * 64 + dw * 16 + hi * 8);
  f32x16 oacc[2][2] = {};  // [qg][dc], partial over this wave's key half

  for (int kb = 0; kb < 16; ++kb) {
    // stage tile kb into the single buffer (prev reads done: trailing barrier)
#pragma unroll
    for (int i = 0; i < 4; ++i)
      GLOAD16(kp[i] + kb * 8192, Sb + i * 2048 + dstoff);
#pragma unroll
    for (int i = 0; i < 4; ++i)
      GLOAD16(vp[i] + kb * 128, Sb + 8192 + i * 2048 + dstoff);
    asm volatile("s_waitcnt vmcnt(0)" ::: "memory");
    __builtin_amdgcn_s_barrier();  // tile staged for all waves
#pragma unroll
    for (int sub = 0; sub < 2; ++sub) {
      const int kb32 = 2 * half + sub;
      const int R = kb32 * 32 + c31;
      bf16x8 kf[4];
#pragma unroll
      for (int dw = 0; dw < 4; ++dw)
        kf[dw] = *(const bf16x8*)(
            Sb + R * 64 + (((2 * dw + hi) ^ (R & 7) ^ ((R >> 3) & 3)) << 3));
      bf16x8 p[2][2];  // [qg][wl]
#pragma unroll
      for (int qg = 0; qg < 2; ++qg) {
        f32x16 s = {};
        __builtin_amdgcn_s_setprio(1);
#pragma unroll
        for (int dw = 0; dw < 4; ++dw)
          s = __builtin_amdgcn_mfma_f32_32x32x16_bf16(kf[dw], qf[qg][dw], s,
                                                      0, 0, 0);
        __builtin_amdgcn_s_setprio(0);
#pragma unroll
        for (int wl = 0; wl < 2; ++wl)
#pragma unroll
          for (int e = 0; e < 8; ++e)
            p[qg][wl][e] = (__bf16)fmaxf(s[8 * wl + e], 0.0f);
      }
      __builtin_amdgcn_s_setprio(1);
#pragma unroll
      for (int wl = 0; wl < 2; ++wl) {
        const int win = 2 * kb32 + wl;
#pragma unroll
        for (int dc = 0; dc < 2; ++dc) {
          const int d = dc * 32 + c31;
          const bf16x8 vb = *(const bf16x8*)(
              Sb + 8192 + d * 128 +
              (((2 * win + hi) ^ (d & 15) ^ ((d >> 3) & 3)) << 3));
          oacc[0][dc] = __builtin_amdgcn_mfma_f32_32x32x16_bf16(
              p[0][wl], vb, oacc[0][dc], 0, 0, 0);
          oacc[1][dc] = __builtin_amdgcn_mfma_f32_32x32x16_bf16(
              p[1][wl], vb, oacc[1][dc], 0, 0, 0);
        }
      }
      __builtin_amdgcn_s_setprio(0);
    }
    __builtin_amdgcn_s_barrier();  // all reads done before next restage
  }
  // ---- pair reduction through LDS (K/V buffer is dead now, 32 KB) ----
  if (half) {
#pragma unroll
    for (int qg = 0; qg < 2; ++qg)
#pragma unroll
      for (int dc = 0; dc < 2; ++dc)
#pragma unroll
        for (int r4 = 0; r4 < 4; ++r4) {
          f32x4 t;
#pragma unroll
          for (int j = 0; j < 4; ++j) t[j] = oacc[qg][dc][r4 * 4 + j];
          *(f32x4*)(redF + pair * 4096 + (qg * 2 + dc) * 1024 + r4 * 256 +
                    lane * 4) = t;
        }
  }
  __builtin_amdgcn_s_barrier();
  if (!half) {
#pragma unroll
    for (int qg = 0; qg < 2; ++qg)
#pragma unroll
      for (int dc = 0; dc < 2; ++dc)
#pragma unroll
        for (int r4 = 0; r4 < 4; ++r4) {
          const f32x4 t = *(const f32x4*)(redF + pair * 4096 +
                                          (qg * 2 + dc) * 1024 + r4 * 256 +
                                          lane * 4);
#pragma unroll
          for (int j = 0; j < 4; ++j) oacc[qg][dc][r4 * 4 + j] += t[j];
        }
    // write O merged-head: [b][n][h*64+d]; q = pair*64+qg*32+(r&3)+8(r>>2)+4hi
    const int bi = bh >> 4, h = bh & 15;
#pragma unroll
    for (int qg = 0; qg < 2; ++qg)
#pragma unroll
      for (int dc = 0; dc < 2; ++dc) {
        const int col = h * 64 + dc * 32 + c31;
#pragma unroll
        for (int r = 0; r < 16; ++r) {
          const int q =
              pair * 64 + qg * 32 + (r & 3) + 8 * (r >> 2) + 4 * hi;
          const int n0 = qb * 128 + q;
          O[((size_t)bi * 2048 + n0) * 1024 + col] = (__bf16)oacc[qg][dc][r];
        }
      }
  }
}

extern "C" void kernel_launch(void* const* d_in, const int* in_sizes, int n_in,
                              void* d_out, int out_size, void* d_ws,
                              size_t ws_size, hipStream_t stream) {
  (void)in_sizes; (void)n_in; (void)out_size; (void)ws_size;
  const float* x = (const float*)d_in[0];
  const float* ln_w = (const float*)d_in[1];
  const float* ln_b = (const float*)d_in[2];
  const float* w_qkv = (const float*)d_in[3];
  const float* w_out = (const float*)d_in[4];
  const float* b_out = (const float*)d_in[5];
  // d_in[6] = layer_index == 2 (< DEPTH/2) -> relu branch only.
  char* ws = (char*)d_ws;
  __bf16* xn = (__bf16*)(ws);                           // 16 MB
  __bf16* Wt1 = (__bf16*)(ws + (size_t)(16u << 20));    // 6 MB  [3072][1024]
  __bf16* Wt2 = (__bf16*)(ws + (size_t)(22u << 20));    // 2 MB  [1024][1024]
  __bf16* Qb = (__bf16*)(ws + (size_t)(24u << 20));     // 16 MB [64][2048][64]
  __bf16* Kb = (__bf16*)(ws + (size_t)(40u << 20));     // 16 MB
  __bf16* Vtb = (__bf16*)(ws + (size_t)(56u << 20));    // 16 MB [64][64][2048]
  __bf16* Ob = (__bf16*)(ws + (size_t)(72u << 20));     // 16 MB [8192][1024]
  float* out = (float*)d_out;

  prep<<<9216, 256, 0, stream>>>(x, ln_w, ln_b, xn, w_qkv, Wt1, w_out, Wt2);
  gemm_nt<0><<<dim3(12, 64), 512, 0, stream>>>(xn, Wt1, 1024, nullptr, Qb, Kb,
                                               Vtb, nullptr);
  attn_relu<<<dim3(64, 16), 256, 0, stream>>>(Qb, Kb, Vtb, Ob);
  gemm_nt<1><<<dim3(4, 64), 512, 0, stream>>>(Ob, Wt2, 1024, out, nullptr,
                                              nullptr, nullptr, b_out);
}

// Round 17
// 159.784 us; speedup vs baseline: 1.5907x; 1.1412x over previous
//
#include <hip/hip_runtime.h>
#include <stdint.h>

typedef __bf16 bf16x8 __attribute__((ext_vector_type(8)));
typedef __bf16 bf16x4 __attribute__((ext_vector_type(4)));
typedef float f32x4 __attribute__((ext_vector_type(4)));

#define PSCALE (0.125f / 2048.0f)

// async global->LDS, 16B per lane. LDS dest must be wave-uniform; HW adds lane*16.
#define GLOAD16(src, dst)                                                      \
  __builtin_amdgcn_global_load_lds(                                            \
      (__attribute__((address_space(1))) void*)const_cast<__bf16*>(src),       \
      (__attribute__((address_space(3))) void*)(dst), 16, 0, 0)

// -------- prep: LayerNorm (blocks 0..8191) + w_qkv transpose (8192..8959)
//          + w_out transpose (8960..9215), all fp32 -> bf16 ----------------
__global__ __launch_bounds__(256) void prep(
    const float* __restrict__ x, const float* __restrict__ lw,
    const float* __restrict__ lb, __bf16* __restrict__ xn,
    const float* __restrict__ w_qkv, __bf16* __restrict__ Wt1,
    const float* __restrict__ w_out, __bf16* __restrict__ Wt2) {
  __shared__ __bf16 T[64][72];
  __shared__ float red[8];
  const int b = blockIdx.x;
  const int t = threadIdx.x;
  if (b < 8192) {  // ---- LayerNorm row b ----
    const float4 v = ((const float4*)(x + (size_t)b * 1024))[t];
    float s = v.x + v.y + v.z + v.w;
    float ss = v.x * v.x + v.y * v.y + v.z * v.z + v.w * v.w;
#pragma unroll
    for (int o = 32; o; o >>= 1) {
      s += __shfl_down(s, o);
      ss += __shfl_down(ss, o);
    }
    if ((t & 63) == 0) {
      red[t >> 6] = s;
      red[4 + (t >> 6)] = ss;
    }
    __syncthreads();
    const float tot = red[0] + red[1] + red[2] + red[3];
    const float tot2 = red[4] + red[5] + red[6] + red[7];
    const float mu = tot * (1.0f / 1024.0f);
    const float var = tot2 * (1.0f / 1024.0f) - mu * mu;
    const float rs = rsqrtf(var + 1e-5f);
    const float4 wv = ((const float4*)lw)[t];
    const float4 bv = ((const float4*)lb)[t];
    bf16x4 o;
    o[0] = (__bf16)((v.x - mu) * rs * wv.x + bv.x);
    o[1] = (__bf16)((v.y - mu) * rs * wv.y + bv.y);
    o[2] = (__bf16)((v.z - mu) * rs * wv.z + bv.z);
    o[3] = (__bf16)((v.w - mu) * rs * wv.w + bv.w);
    ((bf16x4*)xn)[(size_t)b * 256 + t] = o;
    return;
  }
  // ---- transpose+cvt 64x64 tile: A[R][C] -> At[C][R] ----
  const float* A;
  __bf16* At;
  int R, C, bx, by;
  if (b < 8960) {
    const int ti = b - 8192;           // 768 tiles: 48 x 16
    A = w_qkv; At = Wt1; R = 1024; C = 3072;
    bx = ti % 48; by = ti / 48;
  } else {
    const int ti = b - 8960;           // 256 tiles: 16 x 16
    A = w_out; At = Wt2; R = 1024; C = 1024;
    bx = ti % 16; by = ti / 16;
  }
  const int rb = by * 64, cb = bx * 64;
  const int r = t >> 2, cg = t & 3;
#pragma unroll
  for (int k = 0; k < 4; ++k) {
    const float4 v =
        *(const float4*)(A + (size_t)(rb + r) * C + cb + cg * 16 + k * 4);
    T[cg * 16 + k * 4 + 0][r] = (__bf16)v.x;
    T[cg * 16 + k * 4 + 1][r] = (__bf16)v.y;
    T[cg * 16 + k * 4 + 2][r] = (__bf16)v.z;
    T[cg * 16 + k * 4 + 3][r] = (__bf16)v.w;
  }
  __syncthreads();
#pragma unroll
  for (int i = 0; i < 2; ++i) {
    const int j = i * 256 + t;
    const int c = j >> 3, s8 = j & 7;
    const bf16x8 o = *(const bf16x8*)&T[c][s8 * 8];
    *(bf16x8*)(At + (size_t)(cb + c) * R + rb + s8 * 8) = o;
  }
}

// ---- stage a [128 rows][64 k] bf16 tile into LDS, swizzled source (rule 21)
__device__ __forceinline__ void stage_128x64(const __bf16* __restrict__ g,
                                             int ld, __bf16* lds) {
  const int lane = threadIdx.x & 63, w = threadIdx.x >> 6;
#pragma unroll
  for (int i = 0; i < 4; ++i) {
    const int j = i * 256 + w * 64 + lane;  // 1024 chunks of 16B
    const int row = j >> 3, slot = j & 7;
    const __bf16* src = g + (size_t)row * ld + ((slot ^ (row & 7)) << 3);
    GLOAD16(src, lds + (size_t)(i * 256 + w * 64) * 8);
  }
}

// ---------------- NT-GEMM v2: C[M][N] = A[M][K] * B[N][K]^T ----------------
// 128x256 tile, BK=64, 512 threads / 8 waves (2 row x 4 col), wave tile 64x64.
// 3-buffer LDS (144 KB), lead-2 staging with counted vmcnt(6); staging issue
// split around the ks=0 MFMA block so VMEM issue overlaps MFMA.
// XCD-chunked block remap (nwg%8==0): each XCD gets nwg/8 consecutive tiles.
// MODE 0: QKV split epilogue (Q pre-scaled by PSCALE). MODE 1: fp32 + bias.
template <int MODE>
__global__ __launch_bounds__(512) void gemm_nt(
    const __bf16* __restrict__ A, const __bf16* __restrict__ B, int K,
    float* __restrict__ outF, __bf16* __restrict__ Qo, __bf16* __restrict__ Ko,
    __bf16* __restrict__ Vto, const float* __restrict__ bias) {
  __shared__ __bf16 Sm[3 * 24576];  // per buf: A[128][64] @0, B[256][64] @8192
  const int tid = threadIdx.x;
  const int lane = tid & 63, w = tid >> 6;
  const int g = lane >> 4, c15 = lane & 15;
  const int wr = w >> 2, wc = w & 3;  // wave tile: rows wr*64, cols wc*64
  // XCD-chunked bijective remap (gridDim.x*gridDim.y % 8 == 0)
  const int linear = blockIdx.y * gridDim.x + blockIdx.x;
  const int per = (gridDim.x * gridDim.y) >> 3;
  const int nl = (linear & 7) * per + (linear >> 3);
  const int rb = (nl / gridDim.x) * 128, cb = (nl % gridDim.x) * 256;

  // hoisted staging sources: 6 chunks/thread/K-tile (2 A + 4 B), XOR-swizzled
  // source so LDS chunk (row, slot) holds k-chunk slot^(row&7) (rule 21).
  const __bf16* aSp[2];
  const __bf16* bSp[4];
  int aDo[2], bDo[4];
#pragma unroll
  for (int i = 0; i < 2; ++i) {
    const int j = i * 512 + tid, row = j >> 3, slot = j & 7;
    aSp[i] = A + (size_t)(rb + row) * K + ((slot ^ (row & 7)) << 3);
    aDo[i] = i * 4096 + w * 512;
  }
#pragma unroll
  for (int i = 0; i < 4; ++i) {
    const int j = i * 512 + tid, col = j >> 3, slot = j & 7;
    bSp[i] = B + (size_t)(cb + col) * K + ((slot ^ (col & 7)) << 3);
    bDo[i] = 8192 + i * 4096 + w * 512;
  }

  f32x4 acc[4][4] = {};
  const int nkb = K >> 6;  // 16

  // prologue: stage tiles 0,1 into bufs 0,1 (12 loads/thread outstanding)
#pragma unroll
  for (int t = 0; t < 2; ++t) {
    __bf16* dst = Sm + t * 24576;
#pragma unroll
    for (int i = 0; i < 2; ++i) GLOAD16(aSp[i] + t * 64, dst + aDo[i]);
#pragma unroll
    for (int i = 0; i < 4; ++i) GLOAD16(bSp[i] + t * 64, dst + bDo[i]);
  }

  int cur = 0, stg = 2, koff = 128;  // stage target tile = kb+2, k-offset
  for (int kb = 0; kb < nkb; ++kb) {
    if (kb == nkb - 1) {
      asm volatile("s_waitcnt vmcnt(0)" ::: "memory");
    } else {
      asm volatile("s_waitcnt vmcnt(6)" ::: "memory");
    }
    __builtin_amdgcn_s_barrier();  // tile kb staged & prior tenant reads done
    const bool do_stage = (kb < nkb - 2);
    __bf16* sdst = Sm + stg * 24576;
    if (do_stage) {
#pragma unroll
      for (int i = 0; i < 2; ++i) GLOAD16(aSp[i] + koff, sdst + aDo[i]);
    }
    const __bf16* __restrict__ Ac = Sm + cur * 24576;
    const __bf16* __restrict__ Bc = Ac + 8192;
    // ks = 0
    {
      bf16x8 af[4], bfr[4];
      const int kc = g;
#pragma unroll
      for (int rt = 0; rt < 4; ++rt) {
        const int lr = wr * 64 + rt * 16 + c15;
        af[rt] = *(const bf16x8*)(Ac + lr * 64 + ((kc ^ (lr & 7)) << 3));
      }
#pragma unroll
      for (int ct = 0; ct < 4; ++ct) {
        const int lc = wc * 64 + ct * 16 + c15;
        bfr[ct] = *(const bf16x8*)(Bc + lc * 64 + ((kc ^ (lc & 7)) << 3));
      }
      __builtin_amdgcn_s_setprio(1);
#pragma unroll
      for (int rt = 0; rt < 4; ++rt)
#pragma unroll
        for (int ct = 0; ct < 4; ++ct)
          acc[rt][ct] = __builtin_amdgcn_mfma_f32_16x16x32_bf16(
              af[rt], bfr[ct], acc[rt][ct], 0, 0, 0);
      __builtin_amdgcn_s_setprio(0);
    }
    if (do_stage) {
#pragma unroll
      for (int i = 0; i < 4; ++i) GLOAD16(bSp[i] + koff, sdst + bDo[i]);
      koff += 64;
    }
    // ks = 1
    {
      bf16x8 af[4], bfr[4];
      const int kc = 4 + g;
#pragma unroll
      for (int rt = 0; rt < 4; ++rt) {
        const int lr = wr * 64 + rt * 16 + c15;
        af[rt] = *(const bf16x8*)(Ac + lr * 64 + ((kc ^ (lr & 7)) << 3));
      }
#pragma unroll
      for (int ct = 0; ct < 4; ++ct) {
        const int lc = wc * 64 + ct * 16 + c15;
        bfr[ct] = *(const bf16x8*)(Bc + lc * 64 + ((kc ^ (lc & 7)) << 3));
      }
      __builtin_amdgcn_s_setprio(1);
#pragma unroll
      for (int rt = 0; rt < 4; ++rt)
#pragma unroll
        for (int ct = 0; ct < 4; ++ct)
          acc[rt][ct] = __builtin_amdgcn_mfma_f32_16x16x32_bf16(
              af[rt], bfr[ct], acc[rt][ct], 0, 0, 0);
      __builtin_amdgcn_s_setprio(0);
    }
    cur = (cur == 2) ? 0 : cur + 1;
    stg = (stg == 2) ? 0 : stg + 1;
  }
  // epilogue: C row = rb+wr*64+rt*16+g*4+r, col = cb+wc*64+ct*16+c15
  const int r00 = rb + wr * 64 + g * 4;
  if (MODE == 1) {
#pragma unroll
    for (int ct = 0; ct < 4; ++ct) {
      const int col = cb + wc * 64 + ct * 16 + c15;
      const float bv = bias[col];
#pragma unroll
      for (int rt = 0; rt < 4; ++rt) {
        const int row = r00 + rt * 16;
#pragma unroll
        for (int r = 0; r < 4; ++r)
          outF[(size_t)(row + r) * 1024 + col] = acc[rt][ct][r] + bv;
      }
    }
  } else {
#pragma unroll
    for (int ct = 0; ct < 4; ++ct) {
      const int col = cb + wc * 64 + ct * 16 + c15;  // 0..3071
      const int part = col >> 10, rem = col & 1023;
      const int h = rem >> 6, d = rem & 63;
#pragma unroll
      for (int rt = 0; rt < 4; ++rt) {
        const int row = r00 + rt * 16;  // 0..8191
        const int bi = row >> 11, n = row & 2047;
        const size_t bh = (size_t)bi * 16 + h;
        if (part == 2) {  // V stored transposed: Vt[bh][d][n]
          bf16x4 pv;
#pragma unroll
          for (int r = 0; r < 4; ++r) pv[r] = (__bf16)acc[rt][ct][r];
          *(bf16x4*)(Vto + (bh * 64 + d) * 2048 + n) = pv;
        } else if (part == 0) {  // Q: [bh][n][d], pre-scaled by PSCALE
          __bf16* dst = Qo + (bh * 2048 + n) * 64 + d;
#pragma unroll
          for (int r = 0; r < 4; ++r)
            dst[(size_t)r * 64] = (__bf16)(acc[rt][ct][r] * PSCALE);
        } else {  // K: [bh][n][d]
          __bf16* dst = Ko + (bh * 2048 + n) * 64 + d;
#pragma unroll
          for (int r = 0; r < 4; ++r) dst[(size_t)r * 64] = (__bf16)acc[rt][ct][r];
        }
      }
    }
  }
}

// ------------- fused relu-attention: O = relu(Q' K^T) @ V  (Q' pre-scaled) --
// v5 (best measured: 63.4 us): 512 threads / 8 waves, 32 q per wave
// (4 waves/SIMD), K row-permuted in LDS (kappa: b4b3b2 <- b3b2b4) so the two
// QK^T MFMAs of each 32-key group leave lane g holding keys 32u+8g+0..7 ==
// the K=32 PV A-fragment; V consumed as conflict-free b128 B-fragments.
// Double-buffered K/V tiles with counted vmcnt(4); setprio around MFMA
// clusters; hoisted staging pointers. grid (x=bh, y=qb): XCD=bh%8 ->
// per-XCD K/V set = 4MB = its L2.
__global__ __launch_bounds__(512) void attn_relu(
    const __bf16* __restrict__ Q, const __bf16* __restrict__ K,
    const __bf16* __restrict__ Vt, __bf16* __restrict__ O) {
  __shared__ __bf16 Ks[2][128 * 64];   // 2 x 16 KB
  __shared__ __bf16 Vs[2][64 * 128];   // 2 x 16 KB
  const int tid = threadIdx.x;
  const int lane = tid & 63, w = tid >> 6;  // w: 0..7
  const int g = lane >> 4, c15 = lane & 15;
  const int bh = blockIdx.x, qb = blockIdx.y;
  const __bf16* Qg = Q + ((size_t)bh * 2048 + qb * 256) * 64;
  const __bf16* Kg = K + (size_t)bh * 2048 * 64;
  const __bf16* Vg = Vt + (size_t)bh * 64 * 2048;

  // hoisted per-thread staging sources (1024 16B chunks per tile, 512 thr):
  // K: LDS row X holds global key kappa(X) = b4b3b2<-b3b2b4; slot s holds
  //    global d-chunk s ^ (X&7).
  // V: LDS chunk (d, slot) holds global key-chunk (slot ^ (d&15)).
  const __bf16* kp0;
  const __bf16* kp1;
  const __bf16* vp0;
  const __bf16* vp1;
  {
    const int j0 = tid, j1 = 512 + tid;
    const int r0_ = j0 >> 3, s0_ = j0 & 7;
    const int r1_ = j1 >> 3, s1_ = j1 & 7;
    const int sr0 = (r0_ & 96) | ((r0_ & 12) << 1) | ((r0_ & 16) >> 2) | (r0_ & 3);
    const int sr1 = (r1_ & 96) | ((r1_ & 12) << 1) | ((r1_ & 16) >> 2) | (r1_ & 3);
    kp0 = Kg + (size_t)sr0 * 64 + ((s0_ ^ (r0_ & 7)) << 3);
    kp1 = Kg + (size_t)sr1 * 64 + ((s1_ ^ (r1_ & 7)) << 3);
    const int d0_ = j0 >> 4, t0_ = j0 & 15;
    const int d1_ = j1 >> 4, t1_ = j1 & 15;
    vp0 = Vg + (size_t)d0_ * 2048 + ((t0_ ^ (d0_ & 15)) << 3);
    vp1 = Vg + (size_t)d1_ * 2048 + ((t1_ ^ (d1_ & 15)) << 3);
  }
  const int dstoff = w * 64 * 8;  // wave-uniform LDS chunk base (elements)

  bf16x8 qf[2][2];  // wave's 32 q-rows as B-fragments (col=q=lane&15)
#pragma unroll
  for (int rt = 0; rt < 2; ++rt)
#pragma unroll
    for (int ks = 0; ks < 2; ++ks) {
      const int row = w * 32 + rt * 16 + c15;
      qf[rt][ks] = *(const bf16x8*)(Qg + row * 64 + ks * 32 + (g << 3));
    }
  f32x4 oacc[2][4] = {};

  // prologue: stage tile 0 into buffer 0 (4 gload_lds per thread per tile)
  GLOAD16(kp0, Ks[0] + dstoff);
  GLOAD16(kp1, Ks[0] + 512 * 8 + dstoff);
  GLOAD16(vp0, Vs[0] + dstoff);
  GLOAD16(vp1, Vs[0] + 512 * 8 + dstoff);
  kp0 += 128 * 64; kp1 += 128 * 64; vp0 += 128; vp1 += 128;

  for (int kb = 0; kb < 16; ++kb) {
    const int cur = kb & 1;
    if (kb < 15) {
      GLOAD16(kp0, Ks[cur ^ 1] + dstoff);
      GLOAD16(kp1, Ks[cur ^ 1] + 512 * 8 + dstoff);
      GLOAD16(vp0, Vs[cur ^ 1] + dstoff);
      GLOAD16(vp1, Vs[cur ^ 1] + 512 * 8 + dstoff);
      kp0 += 128 * 64; kp1 += 128 * 64; vp0 += 128; vp1 += 128;
      // 8 outstanding (cur 4 + nxt 4) -> wait for the 4 oldest (= cur tile)
      asm volatile("s_waitcnt vmcnt(4)" ::: "memory");
    } else {
      asm volatile("s_waitcnt vmcnt(0)" ::: "memory");
    }
    __builtin_amdgcn_s_barrier();  // cur tile staged for all waves
    const __bf16* __restrict__ Kc = Ks[cur];
    const __bf16* __restrict__ Vc = Vs[cur];
#pragma unroll
    for (int u = 0; u < 4; ++u) {  // 32-key groups
      const int kra = u * 32 + c15;       // LDS rows u*32..+15 (keys permuted)
      const int krb = u * 32 + 16 + c15;  // LDS rows u*32+16..+31
      const bf16x8 kfa0 = *(const bf16x8*)(Kc + kra * 64 + ((g ^ (kra & 7)) << 3));
      const bf16x8 kfa1 = *(const bf16x8*)(Kc + kra * 64 + (((4 + g) ^ (kra & 7)) << 3));
      const bf16x8 kfb0 = *(const bf16x8*)(Kc + krb * 64 + ((g ^ (krb & 7)) << 3));
      const bf16x8 kfb1 = *(const bf16x8*)(Kc + krb * 64 + (((4 + g) ^ (krb & 7)) << 3));
      f32x4 sa[2] = {{}, {}}, sb[2] = {{}, {}};
      __builtin_amdgcn_s_setprio(1);
#pragma unroll
      for (int rt = 0; rt < 2; ++rt) {
        sa[rt] = __builtin_amdgcn_mfma_f32_16x16x32_bf16(kfa0, qf[rt][0], sa[rt], 0, 0, 0);
        sa[rt] = __builtin_amdgcn_mfma_f32_16x16x32_bf16(kfa1, qf[rt][1], sa[rt], 0, 0, 0);
        sb[rt] = __builtin_amdgcn_mfma_f32_16x16x32_bf16(kfb0, qf[rt][0], sb[rt], 0, 0, 0);
        sb[rt] = __builtin_amdgcn_mfma_f32_16x16x32_bf16(kfb1, qf[rt][1], sb[rt], 0, 0, 0);
      }
      __builtin_amdgcn_s_setprio(0);
      // relu -> bf16; lane holds P[q=c15][keys 32u+8g+0..7] = K=32 PV A-frag
      bf16x8 pa[2];
#pragma unroll
      for (int rt = 0; rt < 2; ++rt)
#pragma unroll
        for (int r = 0; r < 4; ++r) {
          pa[rt][r] = (__bf16)fmaxf(sa[rt][r], 0.0f);
          pa[rt][4 + r] = (__bf16)fmaxf(sb[rt][r], 0.0f);
        }
      __builtin_amdgcn_s_setprio(1);
#pragma unroll
      for (int dt = 0; dt < 4; ++dt) {
        const int d = dt * 16 + c15;
        const bf16x8 vb = *(const bf16x8*)(Vc + d * 128 + (((4 * u + g) ^ c15) << 3));
#pragma unroll
        for (int rt = 0; rt < 2; ++rt)
          oacc[rt][dt] = __builtin_amdgcn_mfma_f32_16x16x32_bf16(
              pa[rt], vb, oacc[rt][dt], 0, 0, 0);
      }
      __builtin_amdgcn_s_setprio(0);
    }
    __builtin_amdgcn_s_barrier();  // all waves done reading cur before restage
  }
  // write O merged-head: [b][n][h*64+d] bf16
  const int bi = bh >> 4, h = bh & 15;
#pragma unroll
  for (int rt = 0; rt < 2; ++rt)
#pragma unroll
    for (int dt = 0; dt < 4; ++dt) {
      const int col = h * 64 + dt * 16 + c15;
      const int n0 = qb * 256 + w * 32 + rt * 16 + g * 4;
      __bf16* dst = O + ((size_t)bi * 2048 + n0) * 1024 + col;
#pragma unroll
      for (int r = 0; r < 4; ++r) dst[(size_t)r * 1024] = (__bf16)oacc[rt][dt][r];
    }
}

extern "C" void kernel_launch(void* const* d_in, const int* in_sizes, int n_in,
                              void* d_out, int out_size, void* d_ws,
                              size_t ws_size, hipStream_t stream) {
  (void)in_sizes; (void)n_in; (void)out_size; (void)ws_size;
  const float* x = (const float*)d_in[0];
  const float* ln_w = (const float*)d_in[1];
  const float* ln_b = (const float*)d_in[2];
  const float* w_qkv = (const float*)d_in[3];
  const float* w_out = (const float*)d_in[4];
  const float* b_out = (const float*)d_in[5];
  // d_in[6] = layer_index == 2 (< DEPTH/2) -> relu branch only.
  char* ws = (char*)d_ws;
  __bf16* xn = (__bf16*)(ws);                           // 16 MB
  __bf16* Wt1 = (__bf16*)(ws + (size_t)(16u << 20));    // 6 MB  [3072][1024]
  __bf16* Wt2 = (__bf16*)(ws + (size_t)(22u << 20));    // 2 MB  [1024][1024]
  __bf16* Qb = (__bf16*)(ws + (size_t)(24u << 20));     // 16 MB [64][2048][64]
  __bf16* Kb = (__bf16*)(ws + (size_t)(40u << 20));     // 16 MB
  __bf16* Vtb = (__bf16*)(ws + (size_t)(56u << 20));    // 16 MB [64][64][2048]
  __bf16* Ob = (__bf16*)(ws + (size_t)(72u << 20));     // 16 MB [8192][1024]
  float* out = (float*)d_out;

  prep<<<9216, 256, 0, stream>>>(x, ln_w, ln_b, xn, w_qkv, Wt1, w_out, Wt2);
  gemm_nt<0><<<dim3(12, 64), 512, 0, stream>>>(xn, Wt1, 1024, nullptr, Qb, Kb,
                                               Vtb, nullptr);
  attn_relu<<<dim3(64, 8), 512, 0, stream>>>(Qb, Kb, Vtb, Ob);
  gemm_nt<1><<<dim3(4, 64), 512, 0, stream>>>(Ob, Wt2, 1024, out, nullptr,
                                              nullptr, nullptr, b_out);
}